// Round 10
// baseline (106.895 us; speedup 1.0000x reference)
//
#include <hip/hip_runtime.h>

typedef __bf16 v8bf __attribute__((ext_vector_type(8)));
typedef float v4f __attribute__((ext_vector_type(4)));
typedef unsigned short u16x8 __attribute__((ext_vector_type(8)));

__device__ __forceinline__ unsigned short f2bf(float f) {
    unsigned int u = __float_as_uint(f);
    u += 0x7FFFu + ((u >> 16) & 1u);   // round-to-nearest-even
    return (unsigned short)(u >> 16);
}

__device__ __forceinline__ v8bf ld_bf8(const unsigned short* p) {
    u16x8 r = *(const u16x8*)p;
    return __builtin_bit_cast(v8bf, r);
}

// HW trig: v_cos/v_sin take revolutions. Args h in [0,pi] -> rev in [0,0.5].
__device__ __forceinline__ float hw_cos(float h) {
    float r = h * 0.15915494309189535f, o;
    asm("v_cos_f32 %0, %1" : "=v"(o) : "v"(r));
    return o;
}
__device__ __forceinline__ float hw_sin(float h) {
    float r = h * 0.15915494309189535f, o;
    asm("v_sin_f32 %0, %1" : "=v"(o) : "v"(r));
    return o;
}

// ---------------- Kernel A: build V = U[:, :64], one WAVE per column ----------------
// r5-verified math + r8-verified hw trig (build dropped ~65us -> ~5us in r8).
__global__ __launch_bounds__(64, 2) void build_V(
        const float* __restrict__ rx0, const float* __restrict__ ry0,
        const float* __restrict__ ry1,
        unsigned short* __restrict__ Vre, unsigned short* __restrict__ Vim)
{
    const int c = blockIdx.x;          // column 0..63
    const int lane = threadIdx.x;      // 0..63

    float c1[10], s1[10];
    #pragma unroll
    for (int j = 0; j < 10; ++j) {
        float h = 0.5f * ry1[j];
        c1[j] = hw_cos(h); s1[j] = hw_sin(h);
    }

    int kk[16];
    #pragma unroll
    for (int q = 0; q < 16; ++q) {
        int k = lane + (q << 6);
        #pragma unroll
        for (int jj = 9; jj >= 0; --jj) {
            int cb = 9 - jj, tb = 9 - ((jj + 1) % 10);
            k ^= ((k >> cb) & 1) << tb;
        }
        kk[q] = k;
    }

    float ar[16], ai[16];
    #pragma unroll
    for (int q = 0; q < 16; ++q) { ar[q] = 1.f; ai[q] = 0.f; }

    #pragma unroll
    for (int j = 0; j < 10; ++j) {
        float hx = 0.5f * rx0[j], hy = 0.5f * ry0[j];
        float cx = hw_cos(hx), sx = hw_sin(hx), cy = hw_cos(hy), sy = hw_sin(hy);
        int cb = (c >> (9 - j)) & 1;
        float g0r = cb ? (-sy * cx) : (cy * cx);
        float g0i = cb ? (-cy * sx) : (sy * sx);
        float g1r = cb ? (cy * cx)  : (sy * cx);
        float g1i = cb ? (-sy * sx) : (-cy * sx);
        int p = 9 - j;
        #pragma unroll
        for (int q = 0; q < 16; ++q) {
            int kb = (kk[q] >> p) & 1;
            float fr = kb ? g1r : g0r;
            float fi = kb ? g1i : g0i;
            float nr = ar[q] * fr - ai[q] * fi;
            float ni = ar[q] * fi + ai[q] * fr;
            ar[q] = nr; ai[q] = ni;
        }
    }

    #pragma unroll
    for (int b = 0; b < 4; ++b) {
        float cy = c1[3 - b], sy = s1[3 - b];
        #pragma unroll
        for (int q = 0; q < 16; ++q) {
            if (q & (1 << b)) continue;
            int q2 = q | (1 << b);
            float A_r = ar[q], A_i = ai[q], B_r = ar[q2], B_i = ai[q2];
            ar[q]  = cy * A_r - sy * B_r;  ai[q]  = cy * A_i - sy * B_i;
            ar[q2] = sy * A_r + cy * B_r;  ai[q2] = sy * A_i + cy * B_i;
        }
    }
    #pragma unroll
    for (int p = 5; p >= 0; --p) {
        float cy = c1[9 - p], sy = s1[9 - p];
        int hi = (lane >> p) & 1;
        #pragma unroll
        for (int q = 0; q < 16; ++q) {
            float orr = __shfl_xor(ar[q], 1 << p);
            float oii = __shfl_xor(ai[q], 1 << p);
            ar[q] = hi ? (sy * orr + cy * ar[q]) : (cy * ar[q] - sy * orr);
            ai[q] = hi ? (sy * oii + cy * ai[q]) : (cy * ai[q] - sy * oii);
        }
    }

    #pragma unroll
    for (int q = 0; q < 16; ++q) {
        int i = lane + (q << 6);
        Vre[i * 64 + c] = f2bf(ar[q]);
        Vim[i * 64 + c] = f2bf(ai[q]);
    }
}

// ---------------- Kernel B: out = WHT_7( fold_128( |xn @ VS^T|^2 ) ) ----------------
// LDS-FREE main loop. 1 wave/block, 16 tokens, grid M/16 = 1024 (4 waves/CU).
// Each lane loads its OWN MFMA B-fragments from global (r3-proven addressing;
// V is L2-replicated per XCD after first touch, so LDS sharing buys nothing).
// 4 named register sets, depth-2 prefetch (issue chunk p+2 while computing p),
// sched_barrier(0) pins after each issue batch (anti-sinking, r3 lesson).
#define MFMA16(a, b, c) __builtin_amdgcn_mfma_f32_16x16x32_bf16(a, b, c, 0, 0, 0)

#define ISSUE(s, c) do {                                                     \
    _Pragma("unroll")                                                        \
    for (int _nb = 0; _nb < 4; ++_nb) {                                      \
        s[_nb*2+0] = ld_bf8(vb + (size_t)(c) * 4096 + _nb * 1024);           \
        s[_nb*2+1] = ld_bf8(vb + (size_t)(c) * 4096 + _nb * 1024 + 32);      \
    }                                                                        \
    __builtin_amdgcn_sched_barrier(0);                                       \
    } while (0)

#define COMP(s, q) do {                                                      \
    _Pragma("unroll")                                                        \
    for (int _nb = 0; _nb < 4; ++_nb) {                                      \
        v4f _z = (v4f){0.f, 0.f, 0.f, 0.f};                                  \
        v4f _r = MFMA16(a0, s[_nb*2+0], _z);                                 \
        _r     = MFMA16(a1, s[_nb*2+1], _r);                                 \
        _Pragma("unroll")                                                    \
        for (int _rr = 0; _rr < 4; ++_rr)                                    \
            q[_nb][_rr] += _r[_rr] * _r[_rr];                                \
    } } while (0)

// 4-chunk group starting at even base b: chunks b(E), b+1(O), b+2(E), b+3(O)
#define GROUP(b) do {                                                        \
    if ((b) + 2 < 32) ISSUE(sC, (b) + 2);  COMP(sA, qE);                     \
    if ((b) + 3 < 32) ISSUE(sD, (b) + 3);  COMP(sB, qO);                     \
    if ((b) + 4 < 32) ISSUE(sA, (b) + 4);  COMP(sC, qE);                     \
    if ((b) + 5 < 32) ISSUE(sB, (b) + 5);  COMP(sD, qO);                     \
    } while (0)

__global__ __launch_bounds__(64) void qsa_fused(
        const float* __restrict__ x,
        const unsigned short* __restrict__ VS,
        float* __restrict__ out)
{
    const int l = threadIdx.x;           // 0..63, one wave per block
    const int l15 = l & 15, lh = l >> 4;
    const int tb = blockIdx.x * 16;      // this wave's 16 token rows

    // ---- load + normalize 16 tokens into A-fragments ----
    const float* xrow = x + (size_t)(tb + l15) * 64;
    float4 v0 = *(const float4*)(xrow + lh * 8);
    float4 v1 = *(const float4*)(xrow + lh * 8 + 4);
    float4 v2 = *(const float4*)(xrow + 32 + lh * 8);
    float4 v3 = *(const float4*)(xrow + 32 + lh * 8 + 4);
    float ss = v0.x*v0.x + v0.y*v0.y + v0.z*v0.z + v0.w*v0.w
             + v1.x*v1.x + v1.y*v1.y + v1.z*v1.z + v1.w*v1.w
             + v2.x*v2.x + v2.y*v2.y + v2.z*v2.z + v2.w*v2.w
             + v3.x*v3.x + v3.y*v3.y + v3.z*v3.z + v3.w*v3.w;
    ss += __shfl_xor(ss, 16);
    ss += __shfl_xor(ss, 32);
    float rn = rsqrtf(ss);
    u16x8 ua0, ua1;
    ua0[0]=f2bf(v0.x*rn); ua0[1]=f2bf(v0.y*rn); ua0[2]=f2bf(v0.z*rn); ua0[3]=f2bf(v0.w*rn);
    ua0[4]=f2bf(v1.x*rn); ua0[5]=f2bf(v1.y*rn); ua0[6]=f2bf(v1.z*rn); ua0[7]=f2bf(v1.w*rn);
    ua1[0]=f2bf(v2.x*rn); ua1[1]=f2bf(v2.y*rn); ua1[2]=f2bf(v2.z*rn); ua1[3]=f2bf(v2.w*rn);
    ua1[4]=f2bf(v3.x*rn); ua1[5]=f2bf(v3.y*rn); ua1[6]=f2bf(v3.z*rn); ua1[7]=f2bf(v3.w*rn);
    const v8bf a0 = __builtin_bit_cast(v8bf, ua0);
    const v8bf a1 = __builtin_bit_cast(v8bf, ua1);

    // per-lane fragment base: row l15 (+nb*16 per frag), feat-half lh*8
    const unsigned short* vb = VS + (size_t)l15 * 64 + lh * 8;

    float qE[4][4], qO[4][4];
    #pragma unroll
    for (int nb = 0; nb < 4; ++nb)
        #pragma unroll
        for (int rr = 0; rr < 4; ++rr) { qE[nb][rr] = 0.f; qO[nb][rr] = 0.f; }

    v8bf sA[8], sB[8], sC[8], sD[8];

    ISSUE(sA, 0);
    ISSUE(sB, 1);
    GROUP(0);  GROUP(4);  GROUP(8);  GROUP(12);
    GROUP(16); GROUP(20); GROUP(24); GROUP(28);

    // ---- 7-bit WHT per token row (r4/r8-verified epilogue) ----
    #pragma unroll
    for (int rr = 0; rr < 4; ++rr) {
        float w8[8];
        #pragma unroll
        for (int nb = 0; nb < 4; ++nb) { w8[nb] = qE[nb][rr]; w8[4 + nb] = qO[nb][rr]; }

        #pragma unroll
        for (int i = 0; i < 4; ++i) {                 // bit6 (chunk parity)
            float u = w8[i], v = w8[i + 4];
            w8[i] = u + v; w8[i + 4] = u - v;
        }
        #pragma unroll
        for (int g = 0; g < 8; g += 4)                // bit5 (nb bit1)
            #pragma unroll
            for (int i = 0; i < 2; ++i) {
                float u = w8[g + i], v = w8[g + i + 2];
                w8[g + i] = u + v; w8[g + i + 2] = u - v;
            }
        #pragma unroll
        for (int g = 0; g < 8; g += 2) {              // bit4 (nb bit0)
            float u = w8[g], v = w8[g + 1];
            w8[g] = u + v; w8[g + 1] = u - v;
        }
        #pragma unroll
        for (int st = 1; st <= 8; st <<= 1) {         // bits 3..0 (l15) cross-lane
            #pragma unroll
            for (int k = 0; k < 8; ++k) {
                float o = __shfl_xor(w8[k], st);
                w8[k] = (l15 & st) ? (o - w8[k]) : (w8[k] + o);
            }
        }
        float* orow = out + (size_t)(tb + lh * 4 + rr) * 64;
        #pragma unroll
        for (int nb = 0; nb < 4; ++nb)
            if (nb != 0 || l15 != 0) orow[nb * 16 + l15 - 1] = w8[nb];  // m -> h=m-1
        if (l15 == 0) orow[63] = w8[4];                                  // m=64 -> h=63
    }
}

extern "C" void kernel_launch(void* const* d_in, const int* in_sizes, int n_in,
                              void* d_out, int out_size, void* d_ws, size_t ws_size,
                              hipStream_t stream) {
    const float* x   = (const float*)d_in[0];
    const float* rx0 = (const float*)d_in[1];
    const float* ry0 = (const float*)d_in[2];
    const float* ry1 = (const float*)d_in[3];
    float* out = (float*)d_out;

    unsigned short* Vre = (unsigned short*)d_ws;   // 1024x64 bf16
    unsigned short* Vim = Vre + 1024 * 64;         // 1024x64 bf16 (contiguous -> stacked VS)

    const int M = in_sizes[0] / 64;                // tokens (B*T)

    build_V<<<64, 64, 0, stream>>>(rx0, ry0, ry1, Vre, Vim);
    qsa_fused<<<M / 16, 64, 0, stream>>>(x, Vre, out);
}